// Round 18
// baseline (183.500 us; speedup 1.0000x reference)
//
#include <hip/hip_runtime.h>
#include <hip/hip_bf16.h>

#define FDIM 1024
#define BROWS 16384
#define DELTA_C 0.3f
#define LAMB_C 0.0005f

typedef __bf16 bf8v __attribute__((ext_vector_type(8)));
typedef float f4v __attribute__((ext_vector_type(4)));
typedef int i8v __attribute__((ext_vector_type(8)));
typedef unsigned short u16;
typedef u16 u16x8 __attribute__((ext_vector_type(8)));

// ws layout (bytes):
//   0    : f32 wsf[16] (0=hinge);  64: colsum[1024];  4160: pabs[128];  4672: psq[128]
//   8192 : f32 rowacc[16384] (64KB)
//   131072        : wb8   fp8 [32 kg][1024 n][32B] = 1MB ; wb8[(kg*1024+n)*32+e] = fp8(w[kg*32+e][n])
//   131072+1MB    : sktb8 fp8 [32 kg][16384 m][32B] = 16MB; sktb8[(kg*16384+m)*32+e] = fp8(skt[m][kg*32+e])
#define WS_PABS_OFF 4160
#define WS_PSQ_OFF 4672
#define WS_ROWACC_OFF 8192
#define WS_WB8_OFF 131072
#define WS_SKTB8_OFF (131072 + (1u << 20))
#define WS_NEED ((size_t)WS_SKTB8_OFF + ((size_t)1 << 24))

// single 32KB staging buffer + 512B colsum -> 4 blocks/CU
#define SMEM_MAIN (32768 + 512)

__device__ __forceinline__ u16 f2bf(float f) {
  unsigned u = __builtin_bit_cast(unsigned, f);
  u += 0x7fffu + ((u >> 16) & 1u);
  return (u16)(u >> 16);
}

__device__ __forceinline__ void gload_lds16(const void* g, void* l) {
  __builtin_amdgcn_global_load_lds(
      (const __attribute__((address_space(1))) unsigned int*)g,
      (__attribute__((address_space(3))) unsigned int*)l, 16, 0, 0);
}

// ---- merged prep: blocks [0,128) = W stats + fp8 wb8; [128,128+2048) = fp8 sktb8 ----
template <bool FULL>
__global__ __launch_bounds__(256) void prep_all(const float* __restrict__ w,
                                                const float* __restrict__ skt,
                                                float* __restrict__ colsum,
                                                float* __restrict__ pabs,
                                                float* __restrict__ psq,
                                                char* __restrict__ wb8,
                                                char* __restrict__ sktb8) {
  __shared__ float red[8];
  const int t = threadIdx.x;
  const int bid = blockIdx.x;

  if (bid < 128) {
    const int b = bid;
    const int k0 = b * 8;
    const int col = t * 4;
    float wv[8][4];

    float cs0 = 0.f, cs1 = 0.f, cs2 = 0.f, cs3 = 0.f;
    float aacc = 0.f, sacc = 0.f;
#pragma unroll
    for (int i = 0; i < 8; ++i) {
      const int gk = k0 + i;
      const float4 v = *(const float4*)(w + (size_t)gk * FDIM + col);
      wv[i][0] = v.x; wv[i][1] = v.y; wv[i][2] = v.z; wv[i][3] = v.w;
      cs0 += v.x; cs1 += v.y; cs2 += v.z; cs3 += v.w;
      const float d0 = v.x - (gk == col + 0 ? 1.f : 0.f);
      const float d1 = v.y - (gk == col + 1 ? 1.f : 0.f);
      const float d2 = v.z - (gk == col + 2 ? 1.f : 0.f);
      const float d3 = v.w - (gk == col + 3 ? 1.f : 0.f);
      aacc += fabsf(d0) + fabsf(d1) + fabsf(d2) + fabsf(d3);
      sacc += d0 * d0 + d1 * d1 + d2 * d2 + d3 * d3;
    }
    atomicAdd(&colsum[col + 0], cs0);
    atomicAdd(&colsum[col + 1], cs1);
    atomicAdd(&colsum[col + 2], cs2);
    atomicAdd(&colsum[col + 3], cs3);
#pragma unroll
    for (int off = 1; off < 64; off <<= 1) {
      aacc += __shfl_xor(aacc, off);
      sacc += __shfl_xor(sacc, off);
    }
    const int wv_ = t >> 6;
    if ((t & 63) == 0) { red[wv_] = aacc; red[4 + wv_] = sacc; }
    __syncthreads();
    if (t == 0) pabs[b] = red[0] + red[1] + red[2] + red[3];
    if (t == 1) psq[b] = red[4] + red[5] + red[6] + red[7];
    if constexpr (FULL) {
      // wb8[(kg*1024+n)*32 + (b&3)*8 + i] = fp8(w[b*8+i][n]),  kg = b>>2
#pragma unroll
      for (int j = 0; j < 4; ++j) {
        int lo = __builtin_amdgcn_cvt_pk_fp8_f32(wv[0][j], wv[1][j], 0, false);
        lo = __builtin_amdgcn_cvt_pk_fp8_f32(wv[2][j], wv[3][j], lo, true);
        int hi = __builtin_amdgcn_cvt_pk_fp8_f32(wv[4][j], wv[5][j], 0, false);
        hi = __builtin_amdgcn_cvt_pk_fp8_f32(wv[6][j], wv[7][j], hi, true);
        int2 pk; pk.x = lo; pk.y = hi;
        *(int2*)(wb8 + ((size_t)(b >> 2) * 1024 + col + j) * 32 + (b & 3) * 8) = pk;
      }
    }
  } else if constexpr (FULL) {
    // A path: block handles 64 m x 128 k; thread (m = t&63, kg = t>>6) converts 32 k
    const int ab = bid - 128;
    const int mb = ab >> 3, kb = ab & 7;
    const int m0 = mb * 64, k0 = kb * 128, kg0 = kb * 4;
    const int m = t & 63, kg = t >> 6;
    const float* sp = skt + (size_t)(m0 + m) * FDIM + k0 + kg * 32;
    int wds[8];
#pragma unroll
    for (int q = 0; q < 4; ++q) {
      const float4 a = *(const float4*)(sp + q * 8);
      const float4 b = *(const float4*)(sp + q * 8 + 4);
      int w0 = __builtin_amdgcn_cvt_pk_fp8_f32(a.x, a.y, 0, false);
      w0 = __builtin_amdgcn_cvt_pk_fp8_f32(a.z, a.w, w0, true);
      int w1 = __builtin_amdgcn_cvt_pk_fp8_f32(b.x, b.y, 0, false);
      w1 = __builtin_amdgcn_cvt_pk_fp8_f32(b.z, b.w, w1, true);
      wds[2 * q] = w0; wds[2 * q + 1] = w1;
    }
    char* dst = sktb8 + ((size_t)(kg0 + kg) * BROWS + m0 + m) * 32;
    int4 lo; lo.x = wds[0]; lo.y = wds[1]; lo.z = wds[2]; lo.w = wds[3];
    int4 hi; hi.x = wds[4]; hi.y = wds[5]; hi.z = wds[6]; hi.w = wds[7];
    *(int4*)dst = lo;
    *(int4*)(dst + 16) = hi;
  }
}

// ---- main: T = skt @ w via MX-fp8 K=128 MFMA (unit scales). BM=BN=128, BK=128,
// 8 k-steps, SINGLE 32KB buffer (4 blocks/CU, 16 waves/CU). 256 thr = 4 waves
// (2x2), per-wave 64x64 (4x4 of 16x16).
// Buffer: A [4 kg][2 ch][128 m][16B] = 16K; B same at +16K.
__global__ __launch_bounds__(256, 4) void hofel_main_fp8(
    const float* __restrict__ imgp, const float* __restrict__ imgn,
    const char* __restrict__ wb8, const char* __restrict__ sktb8,
    const float* __restrict__ colsum, float* __restrict__ rowacc) {
  extern __shared__ char smem[];
  float* lds_cs = (float*)(smem + 32768);

  const int t = threadIdx.x;
  const int lane = t & 63;
  const int wid = t >> 6;  // 0..3
  const int l15 = lane & 15;
  const int l4 = lane >> 4;

  // XCD swizzle: 1024 blocks; XCD x gets mt in [x*16, x*16+16) (2MB sktb8 slice = L2)
  const int swz = (blockIdx.x & 7) * 128 + (blockIdx.x >> 3);
  const int mt = swz >> 3, ntw = swz & 7;
  const int m0 = mt * 128, n0 = ntw * 128;

  const int wm = (wid >> 1) * 64, wn = (wid & 1) * 64;

  f4v acc[4][4];
#pragma unroll
  for (int mi = 0; mi < 4; ++mi)
#pragma unroll
    for (int ni = 0; ni < 4; ++ni) {
      f4v z = {0.f, 0.f, 0.f, 0.f};
      acc[mi][ni] = z;
    }

  auto stage = [&](int kt) {
#pragma unroll
    for (int r = 0; r < 8; ++r) {
      const int o = r * 4096 + wid * 1024;  // wave-uniform LDS byte offset
      const int ol = o + lane * 16;
      const char* src;
      if (ol < 16384) {  // A: [kg][ch][m][16B]
        const int kg = ol >> 12, ch = (ol >> 11) & 1, m = (ol >> 4) & 127;
        src = sktb8 + ((size_t)(kt * 4 + kg) * BROWS + m0 + m) * 32 + ch * 16;
      } else {           // B: [kg][ch][n][16B]
        const int o2 = ol - 16384;
        const int kg = o2 >> 12, ch = (o2 >> 11) & 1, n = (o2 >> 4) & 127;
        src = wb8 + ((size_t)(kt * 4 + kg) * FDIM + n0 + n) * 32 + ch * 16;
      }
      gload_lds16(src, smem + o);
    }
  };

  // prologue: stage tile 0; colsum -> LDS tail (disjoint from staging region)
  stage(0);
  if (t < 128) lds_cs[t] = colsum[n0 + t];
  __syncthreads();  // drains vmcnt/lgkm -> tile 0 + colsum ready

  for (int kt = 0; kt < 8; ++kt) {
    const char* bA = smem;
    const char* bB = smem + 16384;
    i8v aF[4], bF[4];
#pragma unroll
    for (int mi = 0; mi < 4; ++mi) {
      const int row = wm + mi * 16 + l15;
      const int4 lo = *(const int4*)(bA + l4 * 4096 + row * 16);
      const int4 hi = *(const int4*)(bA + l4 * 4096 + 2048 + row * 16);
      i8v v = {lo.x, lo.y, lo.z, lo.w, hi.x, hi.y, hi.z, hi.w};
      aF[mi] = v;
    }
#pragma unroll
    for (int ni = 0; ni < 4; ++ni) {
      const int row = wn + ni * 16 + l15;
      const int4 lo = *(const int4*)(bB + l4 * 4096 + row * 16);
      const int4 hi = *(const int4*)(bB + l4 * 4096 + 2048 + row * 16);
      i8v v = {lo.x, lo.y, lo.z, lo.w, hi.x, hi.y, hi.z, hi.w};
      bF[ni] = v;
    }
#pragma unroll
    for (int mi = 0; mi < 4; ++mi)
#pragma unroll
      for (int ni = 0; ni < 4; ++ni)
        acc[mi][ni] = __builtin_amdgcn_mfma_scale_f32_16x16x128_f8f6f4(
            aF[mi], bF[ni], acc[mi][ni], 0, 0, 0, 0x7F7F7F7F, 0, 0x7F7F7F7F);

    if (kt < 7) {
      __syncthreads();  // all waves done reading (frags in VGPRs)
      stage(kt + 1);
      __syncthreads();  // staged data visible (drain)
    }
  }

  __syncthreads();  // staging region free for epilogue scratch

  // ---- vectorized epilogue (r8-validated; C/D layout shape-determined) ----
  {
    float(*eT)[68] = (float(*)[68])(smem + wid * 4352);  // per-wave 16x68 f32
    const int r = l15, qb = l4;
#pragma unroll
    for (int mi = 0; mi < 4; ++mi) {
#pragma unroll
      for (int ni = 0; ni < 4; ++ni)
#pragma unroll
        for (int rr = 0; rr < 4; ++rr)
          eT[l4 * 4 + rr][ni * 16 + l15] = acc[mi][ni][rr];
      const int rowg = m0 + wm + mi * 16 + r;
      const float* pr = imgp + (size_t)rowg * FDIM + n0 + wn;
      const float* nr = imgn + (size_t)rowg * FDIM + n0 + wn;
      float part = 0.f;
#pragma unroll
      for (int i = 0; i < 4; ++i) {
        const int q = qb + 4 * i;
        const f4v T = *(const f4v*)&eT[r][q * 4];
        const float4 p = *(const float4*)(pr + q * 4);
        const float4 n = *(const float4*)(nr + q * 4);
        const f4v cs = *(const f4v*)&lds_cs[wn + q * 4];
        part += (p.x - n.x) * (-2.f * T[0] + (p.x + n.x) * cs[0]);
        part += (p.y - n.y) * (-2.f * T[1] + (p.y + n.y) * cs[1]);
        part += (p.z - n.z) * (-2.f * T[2] + (p.z + n.z) * cs[2]);
        part += (p.w - n.w) * (-2.f * T[3] + (p.w + n.w) * cs[3]);
      }
      part += __shfl_xor(part, 16);
      part += __shfl_xor(part, 32);
      if (lane < 16) atomicAdd(rowacc + rowg, part);
      __syncthreads();
    }
  }
}

// ---- fallback (no workspace): bf16 in-kernel convert, correctness-only ----
__global__ __launch_bounds__(512, 4) void hofel_fb(
    const float* __restrict__ skt, const float* __restrict__ imgp,
    const float* __restrict__ imgn, const float* __restrict__ w,
    const float* __restrict__ colsum, float* __restrict__ rowacc) {
  __shared__ u16 ldsT[12288];
  __shared__ float lds_cs[128];
  const int t = threadIdx.x, lane = t & 63, wid = t >> 6;
  const int l15 = lane & 15, l4 = lane >> 4;
  const int swz = (blockIdx.x & 7) * 64 + (blockIdx.x >> 3);
  const int mt = swz >> 3, nt = swz & 7;
  const int m0 = mt * 256, n0 = nt * 128;
  const int wm = (wid >> 1) * 64, wn = (wid & 1) * 64;

  if (t < 128) lds_cs[t] = colsum[n0 + t];
  f4v acc[4][4];
#pragma unroll
  for (int mi = 0; mi < 4; ++mi)
#pragma unroll
    for (int ni = 0; ni < 4; ++ni) {
      f4v z = {0.f, 0.f, 0.f, 0.f};
      acc[mi][ni] = z;
    }

  for (int kt = 0; kt < 32; ++kt) {
    __syncthreads();
    {  // B: ldsB[s][kc][e] = w[kt*32+s*8+e][n0+kc]  (strided, correct)
      const int kc = t >> 2, s = t & 3;
      u16x8 pk;
#pragma unroll
      for (int e = 0; e < 8; ++e)
        pk[e] = f2bf(w[(size_t)(kt * 32 + s * 8 + e) * FDIM + n0 + kc]);
      *(u16x8*)((char*)ldsT + 16384 + (s * 128 + kc) * 16) = pk;
    }
    {  // A from f32 skt
      const int m = t >> 1, h = t & 1;
      const float* ap = skt + (size_t)(m0 + m) * FDIM + kt * 32 + h * 16;
#pragma unroll
      for (int q = 0; q < 2; ++q) {
        const float4 v0 = *(const float4*)(ap + q * 8);
        const float4 v1 = *(const float4*)(ap + q * 8 + 4);
        u16x8 pk;
        pk[0] = f2bf(v0.x); pk[1] = f2bf(v0.y); pk[2] = f2bf(v0.z); pk[3] = f2bf(v0.w);
        pk[4] = f2bf(v1.x); pk[5] = f2bf(v1.y); pk[6] = f2bf(v1.z); pk[7] = f2bf(v1.w);
        *(u16x8*)((char*)ldsT + (h * 2 + q) * 4096 + m * 16) = pk;
      }
    }
    __syncthreads();
    bf8v aF[4], bF[4];
#pragma unroll
    for (int mi = 0; mi < 4; ++mi)
      aF[mi] = *(const bf8v*)((char*)ldsT + l4 * 4096 + (wm + mi * 16 + l15) * 16);
#pragma unroll
    for (int ni = 0; ni < 4; ++ni)
      bF[ni] = *(const bf8v*)((char*)ldsT + 16384 + l4 * 2048 + (wn + ni * 16 + l15) * 16);
#pragma unroll
    for (int mi = 0; mi < 4; ++mi)
#pragma unroll
      for (int ni = 0; ni < 4; ++ni)
        acc[mi][ni] = __builtin_amdgcn_mfma_f32_16x16x32_bf16(aF[mi], bF[ni], acc[mi][ni], 0, 0, 0);
  }
  __syncthreads();
  {
    float(*eT)[68] = (float(*)[68])((char*)ldsT + wid * 4352);
    const int r = l15, qb = l4;
#pragma unroll
    for (int mi = 0; mi < 4; ++mi) {
#pragma unroll
      for (int ni = 0; ni < 4; ++ni)
#pragma unroll
        for (int rr = 0; rr < 4; ++rr)
          eT[l4 * 4 + rr][ni * 16 + l15] = acc[mi][ni][rr];
      const int rowg = m0 + wm + mi * 16 + r;
      const float* pr = imgp + (size_t)rowg * FDIM + n0 + wn;
      const float* nr = imgn + (size_t)rowg * FDIM + n0 + wn;
      float part = 0.f;
#pragma unroll
      for (int i = 0; i < 4; ++i) {
        const int q = qb + 4 * i;
        const f4v T = *(const f4v*)&eT[r][q * 4];
        const float4 p = *(const float4*)(pr + q * 4);
        const float4 n = *(const float4*)(nr + q * 4);
        const f4v cs = *(const f4v*)&lds_cs[wn + q * 4];
        part += (p.x - n.x) * (-2.f * T[0] + (p.x + n.x) * cs[0]);
        part += (p.y - n.y) * (-2.f * T[1] + (p.y + n.y) * cs[1]);
        part += (p.z - n.z) * (-2.f * T[2] + (p.z + n.z) * cs[2]);
        part += (p.w - n.w) * (-2.f * T[3] + (p.w + n.w) * cs[3]);
      }
      part += __shfl_xor(part, 16);
      part += __shfl_xor(part, 32);
      if (lane < 16) atomicAdd(rowacc + rowg, part);
      __syncthreads();
    }
  }
}

__global__ __launch_bounds__(1024) void hinge_reduce(const float* __restrict__ rowacc,
                                                     float* __restrict__ wsf) {
  __shared__ float part[16];
  const int t = threadIdx.x;
  const int id = blockIdx.x * 1024 + t;
  float v = fmaxf(DELTA_C + rowacc[id], 0.f);
#pragma unroll
  for (int off = 1; off < 64; off <<= 1) v += __shfl_xor(v, off);
  if ((t & 63) == 0) part[t >> 6] = v;
  __syncthreads();
  if (t < 16) {
    float x = part[t];
#pragma unroll
    for (int off = 1; off < 16; off <<= 1) x += __shfl_xor(x, off);
    if (t == 0) atomicAdd(&wsf[0], x);
  }
}

__global__ __launch_bounds__(128) void finalize_k(const float* __restrict__ wsf,
                                                  const float* __restrict__ pabs,
                                                  const float* __restrict__ psq,
                                                  float* __restrict__ out) {
  __shared__ float ra[2], rs[2];
  const int t = threadIdx.x;
  float a = pabs[t], s = psq[t];
#pragma unroll
  for (int off = 1; off < 64; off <<= 1) {
    a += __shfl_xor(a, off);
    s += __shfl_xor(s, off);
  }
  if ((t & 63) == 0) { ra[t >> 6] = a; rs[t >> 6] = s; }
  __syncthreads();
  if (t == 0)
    out[0] = wsf[0] * (1.f / (float)BROWS) +
             LAMB_C * ((ra[0] + ra[1]) + sqrtf(rs[0] + rs[1]));
}

extern "C" void kernel_launch(void* const* d_in, const int* in_sizes, int n_in,
                              void* d_out, int out_size, void* d_ws, size_t ws_size,
                              hipStream_t stream) {
  const float* skt  = (const float*)d_in[0];
  const float* imgp = (const float*)d_in[1];
  const float* imgn = (const float*)d_in[2];
  const float* w    = (const float*)d_in[3];

  float* wsf = (float*)d_ws;
  float* colsum = wsf + 16;
  float* pabs = (float*)((char*)d_ws + WS_PABS_OFF);
  float* psq = (float*)((char*)d_ws + WS_PSQ_OFF);
  float* rowacc = (float*)((char*)d_ws + WS_ROWACC_OFF);
  char* wb8 = (char*)d_ws + WS_WB8_OFF;
  char* sktb8 = (char*)d_ws + WS_SKTB8_OFF;
  float* out = (float*)d_out;

  // zero wsf + colsum + pabs/psq + rowacc every call (harness doesn't re-poison)
  hipMemsetAsync(d_ws, 0, WS_ROWACC_OFF + BROWS * sizeof(float), stream);

  if (ws_size >= WS_NEED) {
    prep_all<true><<<128 + 2048, 256, 0, stream>>>(w, skt, colsum, pabs, psq, wb8, sktb8);
    (void)hipFuncSetAttribute(reinterpret_cast<const void*>(hofel_main_fp8),
                              hipFuncAttributeMaxDynamicSharedMemorySize, SMEM_MAIN);
    hofel_main_fp8<<<1024, 256, SMEM_MAIN, stream>>>(imgp, imgn, wb8, sktb8, colsum, rowacc);
  } else {
    prep_all<false><<<128, 256, 0, stream>>>(w, skt, colsum, pabs, psq, wb8, sktb8);
    hofel_fb<<<512, 512, 0, stream>>>(skt, imgp, imgn, w, colsum, rowacc);
  }

  hinge_reduce<<<16, 1024, 0, stream>>>(rowacc, wsf);
  finalize_k<<<1, 128, 0, stream>>>(wsf, pabs, psq, out);
}

// Round 19
// 76.526 us; speedup vs baseline: 2.3979x; 2.3979x over previous
//
#include <hip/hip_runtime.h>
#include <hip/hip_bf16.h>

#define FDIM 1024
#define BROWS 16384
#define DELTA_C 0.3f
#define LAMB_C 0.0005f

typedef __bf16 bf8v __attribute__((ext_vector_type(8)));
typedef float f4v __attribute__((ext_vector_type(4)));
typedef int i8v __attribute__((ext_vector_type(8)));
typedef unsigned short u16;
typedef u16 u16x8 __attribute__((ext_vector_type(8)));

// ws layout (bytes):
//   0    : f32 wsf[16] (0=hinge);  64: colsum[1024];  4160: pabs[128];  4672: psq[128]
//   8192 : f32 rowacc[16384] (64KB)
//   131072        : wb8   fp8 [32 kg][1024 n][32B] = 1MB ; wb8[(kg*1024+n)*32+e] = fp8(w[kg*32+e][n])
//   131072+1MB    : sktb8 fp8 [32 kg][16384 m][32B] = 16MB; sktb8[(kg*16384+m)*32+e] = fp8(skt[m][kg*32+e])
#define WS_PABS_OFF 4160
#define WS_PSQ_OFF 4672
#define WS_ROWACC_OFF 8192
#define WS_WB8_OFF 131072
#define WS_SKTB8_OFF (131072 + (1u << 20))
#define WS_NEED ((size_t)WS_SKTB8_OFF + ((size_t)1 << 24))

// single 32KB staging buffer + 512B colsum -> 4 blocks/CU by LDS
#define SMEM_MAIN (32768 + 512)

__device__ __forceinline__ u16 f2bf(float f) {
  unsigned u = __builtin_bit_cast(unsigned, f);
  u += 0x7fffu + ((u >> 16) & 1u);
  return (u16)(u >> 16);
}

__device__ __forceinline__ void gload_lds16(const void* g, void* l) {
  __builtin_amdgcn_global_load_lds(
      (const __attribute__((address_space(1))) unsigned int*)g,
      (__attribute__((address_space(3))) unsigned int*)l, 16, 0, 0);
}

// ---- merged prep: blocks [0,128) = W stats + fp8 wb8; [128,128+2048) = fp8 sktb8 ----
template <bool FULL>
__global__ __launch_bounds__(256) void prep_all(const float* __restrict__ w,
                                                const float* __restrict__ skt,
                                                float* __restrict__ colsum,
                                                float* __restrict__ pabs,
                                                float* __restrict__ psq,
                                                char* __restrict__ wb8,
                                                char* __restrict__ sktb8) {
  __shared__ float red[8];
  const int t = threadIdx.x;
  const int bid = blockIdx.x;

  if (bid < 128) {
    const int b = bid;
    const int k0 = b * 8;
    const int col = t * 4;
    float wv[8][4];

    float cs0 = 0.f, cs1 = 0.f, cs2 = 0.f, cs3 = 0.f;
    float aacc = 0.f, sacc = 0.f;
#pragma unroll
    for (int i = 0; i < 8; ++i) {
      const int gk = k0 + i;
      const float4 v = *(const float4*)(w + (size_t)gk * FDIM + col);
      wv[i][0] = v.x; wv[i][1] = v.y; wv[i][2] = v.z; wv[i][3] = v.w;
      cs0 += v.x; cs1 += v.y; cs2 += v.z; cs3 += v.w;
      const float d0 = v.x - (gk == col + 0 ? 1.f : 0.f);
      const float d1 = v.y - (gk == col + 1 ? 1.f : 0.f);
      const float d2 = v.z - (gk == col + 2 ? 1.f : 0.f);
      const float d3 = v.w - (gk == col + 3 ? 1.f : 0.f);
      aacc += fabsf(d0) + fabsf(d1) + fabsf(d2) + fabsf(d3);
      sacc += d0 * d0 + d1 * d1 + d2 * d2 + d3 * d3;
    }
    atomicAdd(&colsum[col + 0], cs0);
    atomicAdd(&colsum[col + 1], cs1);
    atomicAdd(&colsum[col + 2], cs2);
    atomicAdd(&colsum[col + 3], cs3);
#pragma unroll
    for (int off = 1; off < 64; off <<= 1) {
      aacc += __shfl_xor(aacc, off);
      sacc += __shfl_xor(sacc, off);
    }
    const int wv_ = t >> 6;
    if ((t & 63) == 0) { red[wv_] = aacc; red[4 + wv_] = sacc; }
    __syncthreads();
    if (t == 0) pabs[b] = red[0] + red[1] + red[2] + red[3];
    if (t == 1) psq[b] = red[4] + red[5] + red[6] + red[7];
    if constexpr (FULL) {
      // wb8[(kg*1024+n)*32 + (b&3)*8 + i] = fp8(w[b*8+i][n]),  kg = b>>2
#pragma unroll
      for (int j = 0; j < 4; ++j) {
        int lo = __builtin_amdgcn_cvt_pk_fp8_f32(wv[0][j], wv[1][j], 0, false);
        lo = __builtin_amdgcn_cvt_pk_fp8_f32(wv[2][j], wv[3][j], lo, true);
        int hi = __builtin_amdgcn_cvt_pk_fp8_f32(wv[4][j], wv[5][j], 0, false);
        hi = __builtin_amdgcn_cvt_pk_fp8_f32(wv[6][j], wv[7][j], hi, true);
        int2 pk; pk.x = lo; pk.y = hi;
        *(int2*)(wb8 + ((size_t)(b >> 2) * 1024 + col + j) * 32 + (b & 3) * 8) = pk;
      }
    }
  } else if constexpr (FULL) {
    // A path: block handles 64 m x 128 k; thread (m = t&63, kg = t>>6) converts 32 k
    const int ab = bid - 128;
    const int mb = ab >> 3, kb = ab & 7;
    const int m0 = mb * 64, k0 = kb * 128, kg0 = kb * 4;
    const int m = t & 63, kg = t >> 6;
    const float* sp = skt + (size_t)(m0 + m) * FDIM + k0 + kg * 32;
    int wds[8];
#pragma unroll
    for (int q = 0; q < 4; ++q) {
      const float4 a = *(const float4*)(sp + q * 8);
      const float4 b = *(const float4*)(sp + q * 8 + 4);
      int w0 = __builtin_amdgcn_cvt_pk_fp8_f32(a.x, a.y, 0, false);
      w0 = __builtin_amdgcn_cvt_pk_fp8_f32(a.z, a.w, w0, true);
      int w1 = __builtin_amdgcn_cvt_pk_fp8_f32(b.x, b.y, 0, false);
      w1 = __builtin_amdgcn_cvt_pk_fp8_f32(b.z, b.w, w1, true);
      wds[2 * q] = w0; wds[2 * q + 1] = w1;
    }
    char* dst = sktb8 + ((size_t)(kg0 + kg) * BROWS + m0 + m) * 32;
    int4 lo; lo.x = wds[0]; lo.y = wds[1]; lo.z = wds[2]; lo.w = wds[3];
    int4 hi; hi.x = wds[4]; hi.y = wds[5]; hi.z = wds[6]; hi.w = wds[7];
    *(int4*)dst = lo;
    *(int4*)(dst + 16) = hi;
  }
}

// ---- main: T = skt @ w via MX-fp8 K=128 MFMA (unit scales). BM=BN=128, BK=128,
// 8 k-steps, SINGLE 32KB buffer; launch_bounds(256,2) so allocator is NOT
// squeezed (r18 lesson: forcing 4 waves/EU spilled acc+frags to scratch).
// Frag-streaming: bF[4] resident, aF loaded one at a time -> peak live ~120 regs.
// 256 thr = 4 waves (2x2), per-wave 64x64 (4x4 of 16x16).
// Buffer: A [4 kg][2 ch][128 m][16B] = 16K; B same at +16K.
__global__ __launch_bounds__(256, 2) void hofel_main_fp8(
    const float* __restrict__ imgp, const float* __restrict__ imgn,
    const char* __restrict__ wb8, const char* __restrict__ sktb8,
    const float* __restrict__ colsum, float* __restrict__ rowacc) {
  extern __shared__ char smem[];
  float* lds_cs = (float*)(smem + 32768);

  const int t = threadIdx.x;
  const int lane = t & 63;
  const int wid = t >> 6;  // 0..3
  const int l15 = lane & 15;
  const int l4 = lane >> 4;

  // XCD swizzle: 1024 blocks; XCD x gets mt in [x*16, x*16+16) (2MB sktb8 slice = L2)
  const int swz = (blockIdx.x & 7) * 128 + (blockIdx.x >> 3);
  const int mt = swz >> 3, ntw = swz & 7;
  const int m0 = mt * 128, n0 = ntw * 128;

  const int wm = (wid >> 1) * 64, wn = (wid & 1) * 64;

  f4v acc[4][4];
#pragma unroll
  for (int mi = 0; mi < 4; ++mi)
#pragma unroll
    for (int ni = 0; ni < 4; ++ni) {
      f4v z = {0.f, 0.f, 0.f, 0.f};
      acc[mi][ni] = z;
    }

  auto stage = [&](int kt) {
#pragma unroll
    for (int r = 0; r < 8; ++r) {
      const int o = r * 4096 + wid * 1024;  // wave-uniform LDS byte offset
      const int ol = o + lane * 16;
      const char* src;
      if (ol < 16384) {  // A: [kg][ch][m][16B]
        const int kg = ol >> 12, ch = (ol >> 11) & 1, m = (ol >> 4) & 127;
        src = sktb8 + ((size_t)(kt * 4 + kg) * BROWS + m0 + m) * 32 + ch * 16;
      } else {           // B: [kg][ch][n][16B]
        const int o2 = ol - 16384;
        const int kg = o2 >> 12, ch = (o2 >> 11) & 1, n = (o2 >> 4) & 127;
        src = wb8 + ((size_t)(kt * 4 + kg) * FDIM + n0 + n) * 32 + ch * 16;
      }
      gload_lds16(src, smem + o);
    }
  };

  // prologue: stage tile 0; colsum -> LDS tail (disjoint from staging region)
  stage(0);
  if (t < 128) lds_cs[t] = colsum[n0 + t];
  __syncthreads();  // drains vmcnt/lgkm -> tile 0 + colsum ready

  for (int kt = 0; kt < 8; ++kt) {
    const char* bA = smem;
    const char* bB = smem + 16384;
    // bF[4] resident (32 VGPRs); aF streamed one at a time (8 VGPRs)
    i8v bF[4];
#pragma unroll
    for (int ni = 0; ni < 4; ++ni) {
      const int row = wn + ni * 16 + l15;
      const int4 lo = *(const int4*)(bB + l4 * 4096 + row * 16);
      const int4 hi = *(const int4*)(bB + l4 * 4096 + 2048 + row * 16);
      i8v v = {lo.x, lo.y, lo.z, lo.w, hi.x, hi.y, hi.z, hi.w};
      bF[ni] = v;
    }
#pragma unroll
    for (int mi = 0; mi < 4; ++mi) {
      const int row = wm + mi * 16 + l15;
      const int4 lo = *(const int4*)(bA + l4 * 4096 + row * 16);
      const int4 hi = *(const int4*)(bA + l4 * 4096 + 2048 + row * 16);
      i8v aF = {lo.x, lo.y, lo.z, lo.w, hi.x, hi.y, hi.z, hi.w};
#pragma unroll
      for (int ni = 0; ni < 4; ++ni)
        acc[mi][ni] = __builtin_amdgcn_mfma_scale_f32_16x16x128_f8f6f4(
            aF, bF[ni], acc[mi][ni], 0, 0, 0, 0x7F7F7F7F, 0, 0x7F7F7F7F);
    }

    if (kt < 7) {
      __syncthreads();  // all waves done reading (frags consumed)
      stage(kt + 1);
      __syncthreads();  // staged data visible (drain)
    }
  }

  __syncthreads();  // staging region free for epilogue scratch

  // ---- vectorized epilogue (r8-validated; C/D layout shape-determined) ----
  {
    float(*eT)[68] = (float(*)[68])(smem + wid * 4352);  // per-wave 16x68 f32
    const int r = l15, qb = l4;
#pragma unroll
    for (int mi = 0; mi < 4; ++mi) {
#pragma unroll
      for (int ni = 0; ni < 4; ++ni)
#pragma unroll
        for (int rr = 0; rr < 4; ++rr)
          eT[l4 * 4 + rr][ni * 16 + l15] = acc[mi][ni][rr];
      const int rowg = m0 + wm + mi * 16 + r;
      const float* pr = imgp + (size_t)rowg * FDIM + n0 + wn;
      const float* nr = imgn + (size_t)rowg * FDIM + n0 + wn;
      float part = 0.f;
#pragma unroll
      for (int i = 0; i < 4; ++i) {
        const int q = qb + 4 * i;
        const f4v T = *(const f4v*)&eT[r][q * 4];
        const float4 p = *(const float4*)(pr + q * 4);
        const float4 n = *(const float4*)(nr + q * 4);
        const f4v cs = *(const f4v*)&lds_cs[wn + q * 4];
        part += (p.x - n.x) * (-2.f * T[0] + (p.x + n.x) * cs[0]);
        part += (p.y - n.y) * (-2.f * T[1] + (p.y + n.y) * cs[1]);
        part += (p.z - n.z) * (-2.f * T[2] + (p.z + n.z) * cs[2]);
        part += (p.w - n.w) * (-2.f * T[3] + (p.w + n.w) * cs[3]);
      }
      part += __shfl_xor(part, 16);
      part += __shfl_xor(part, 32);
      if (lane < 16) atomicAdd(rowacc + rowg, part);
      __syncthreads();
    }
  }
}

// ---- fallback (no workspace): bf16 in-kernel convert, correctness-only ----
__global__ __launch_bounds__(512, 4) void hofel_fb(
    const float* __restrict__ skt, const float* __restrict__ imgp,
    const float* __restrict__ imgn, const float* __restrict__ w,
    const float* __restrict__ colsum, float* __restrict__ rowacc) {
  __shared__ u16 ldsT[12288];
  __shared__ float lds_cs[128];
  const int t = threadIdx.x, lane = t & 63, wid = t >> 6;
  const int l15 = lane & 15, l4 = lane >> 4;
  const int swz = (blockIdx.x & 7) * 64 + (blockIdx.x >> 3);
  const int mt = swz >> 3, nt = swz & 7;
  const int m0 = mt * 256, n0 = nt * 128;
  const int wm = (wid >> 1) * 64, wn = (wid & 1) * 64;

  if (t < 128) lds_cs[t] = colsum[n0 + t];
  f4v acc[4][4];
#pragma unroll
  for (int mi = 0; mi < 4; ++mi)
#pragma unroll
    for (int ni = 0; ni < 4; ++ni) {
      f4v z = {0.f, 0.f, 0.f, 0.f};
      acc[mi][ni] = z;
    }

  for (int kt = 0; kt < 32; ++kt) {
    __syncthreads();
    {  // B: ldsB[s][kc][e] = w[kt*32+s*8+e][n0+kc]  (strided, correct)
      const int kc = t >> 2, s = t & 3;
      u16x8 pk;
#pragma unroll
      for (int e = 0; e < 8; ++e)
        pk[e] = f2bf(w[(size_t)(kt * 32 + s * 8 + e) * FDIM + n0 + kc]);
      *(u16x8*)((char*)ldsT + 16384 + (s * 128 + kc) * 16) = pk;
    }
    {  // A from f32 skt
      const int m = t >> 1, h = t & 1;
      const float* ap = skt + (size_t)(m0 + m) * FDIM + kt * 32 + h * 16;
#pragma unroll
      for (int q = 0; q < 2; ++q) {
        const float4 v0 = *(const float4*)(ap + q * 8);
        const float4 v1 = *(const float4*)(ap + q * 8 + 4);
        u16x8 pk;
        pk[0] = f2bf(v0.x); pk[1] = f2bf(v0.y); pk[2] = f2bf(v0.z); pk[3] = f2bf(v0.w);
        pk[4] = f2bf(v1.x); pk[5] = f2bf(v1.y); pk[6] = f2bf(v1.z); pk[7] = f2bf(v1.w);
        *(u16x8*)((char*)ldsT + (h * 2 + q) * 4096 + m * 16) = pk;
      }
    }
    __syncthreads();
    bf8v aF[4], bF[4];
#pragma unroll
    for (int mi = 0; mi < 4; ++mi)
      aF[mi] = *(const bf8v*)((char*)ldsT + l4 * 4096 + (wm + mi * 16 + l15) * 16);
#pragma unroll
    for (int ni = 0; ni < 4; ++ni)
      bF[ni] = *(const bf8v*)((char*)ldsT + 16384 + l4 * 2048 + (wn + ni * 16 + l15) * 16);
#pragma unroll
    for (int mi = 0; mi < 4; ++mi)
#pragma unroll
      for (int ni = 0; ni < 4; ++ni)
        acc[mi][ni] = __builtin_amdgcn_mfma_f32_16x16x32_bf16(aF[mi], bF[ni], acc[mi][ni], 0, 0, 0);
  }
  __syncthreads();
  {
    float(*eT)[68] = (float(*)[68])((char*)ldsT + wid * 4352);
    const int r = l15, qb = l4;
#pragma unroll
    for (int mi = 0; mi < 4; ++mi) {
#pragma unroll
      for (int ni = 0; ni < 4; ++ni)
#pragma unroll
        for (int rr = 0; rr < 4; ++rr)
          eT[l4 * 4 + rr][ni * 16 + l15] = acc[mi][ni][rr];
      const int rowg = m0 + wm + mi * 16 + r;
      const float* pr = imgp + (size_t)rowg * FDIM + n0 + wn;
      const float* nr = imgn + (size_t)rowg * FDIM + n0 + wn;
      float part = 0.f;
#pragma unroll
      for (int i = 0; i < 4; ++i) {
        const int q = qb + 4 * i;
        const f4v T = *(const f4v*)&eT[r][q * 4];
        const float4 p = *(const float4*)(pr + q * 4);
        const float4 n = *(const float4*)(nr + q * 4);
        const f4v cs = *(const f4v*)&lds_cs[wn + q * 4];
        part += (p.x - n.x) * (-2.f * T[0] + (p.x + n.x) * cs[0]);
        part += (p.y - n.y) * (-2.f * T[1] + (p.y + n.y) * cs[1]);
        part += (p.z - n.z) * (-2.f * T[2] + (p.z + n.z) * cs[2]);
        part += (p.w - n.w) * (-2.f * T[3] + (p.w + n.w) * cs[3]);
      }
      part += __shfl_xor(part, 16);
      part += __shfl_xor(part, 32);
      if (lane < 16) atomicAdd(rowacc + rowg, part);
      __syncthreads();
    }
  }
}

__global__ __launch_bounds__(1024) void hinge_reduce(const float* __restrict__ rowacc,
                                                     float* __restrict__ wsf) {
  __shared__ float part[16];
  const int t = threadIdx.x;
  const int id = blockIdx.x * 1024 + t;
  float v = fmaxf(DELTA_C + rowacc[id], 0.f);
#pragma unroll
  for (int off = 1; off < 64; off <<= 1) v += __shfl_xor(v, off);
  if ((t & 63) == 0) part[t >> 6] = v;
  __syncthreads();
  if (t < 16) {
    float x = part[t];
#pragma unroll
    for (int off = 1; off < 16; off <<= 1) x += __shfl_xor(x, off);
    if (t == 0) atomicAdd(&wsf[0], x);
  }
}

__global__ __launch_bounds__(128) void finalize_k(const float* __restrict__ wsf,
                                                  const float* __restrict__ pabs,
                                                  const float* __restrict__ psq,
                                                  float* __restrict__ out) {
  __shared__ float ra[2], rs[2];
  const int t = threadIdx.x;
  float a = pabs[t], s = psq[t];
#pragma unroll
  for (int off = 1; off < 64; off <<= 1) {
    a += __shfl_xor(a, off);
    s += __shfl_xor(s, off);
  }
  if ((t & 63) == 0) { ra[t >> 6] = a; rs[t >> 6] = s; }
  __syncthreads();
  if (t == 0)
    out[0] = wsf[0] * (1.f / (float)BROWS) +
             LAMB_C * ((ra[0] + ra[1]) + sqrtf(rs[0] + rs[1]));
}

extern "C" void kernel_launch(void* const* d_in, const int* in_sizes, int n_in,
                              void* d_out, int out_size, void* d_ws, size_t ws_size,
                              hipStream_t stream) {
  const float* skt  = (const float*)d_in[0];
  const float* imgp = (const float*)d_in[1];
  const float* imgn = (const float*)d_in[2];
  const float* w    = (const float*)d_in[3];

  float* wsf = (float*)d_ws;
  float* colsum = wsf + 16;
  float* pabs = (float*)((char*)d_ws + WS_PABS_OFF);
  float* psq = (float*)((char*)d_ws + WS_PSQ_OFF);
  float* rowacc = (float*)((char*)d_ws + WS_ROWACC_OFF);
  char* wb8 = (char*)d_ws + WS_WB8_OFF;
  char* sktb8 = (char*)d_ws + WS_SKTB8_OFF;
  float* out = (float*)d_out;

  // zero wsf + colsum + pabs/psq + rowacc every call (harness doesn't re-poison)
  hipMemsetAsync(d_ws, 0, WS_ROWACC_OFF + BROWS * sizeof(float), stream);

  if (ws_size >= WS_NEED) {
    prep_all<true><<<128 + 2048, 256, 0, stream>>>(w, skt, colsum, pabs, psq, wb8, sktb8);
    (void)hipFuncSetAttribute(reinterpret_cast<const void*>(hofel_main_fp8),
                              hipFuncAttributeMaxDynamicSharedMemorySize, SMEM_MAIN);
    hofel_main_fp8<<<1024, 256, SMEM_MAIN, stream>>>(imgp, imgn, wb8, sktb8, colsum, rowacc);
  } else {
    prep_all<false><<<128, 256, 0, stream>>>(w, skt, colsum, pabs, psq, wb8, sktb8);
    hofel_fb<<<512, 512, 0, stream>>>(skt, imgp, imgn, w, colsum, rowacc);
  }

  hinge_reduce<<<16, 1024, 0, stream>>>(rowacc, wsf);
  finalize_k<<<1, 128, 0, stream>>>(wsf, pabs, psq, out);
}

// Round 20
// 75.315 us; speedup vs baseline: 2.4364x; 1.0161x over previous
//
#include <hip/hip_runtime.h>
#include <hip/hip_bf16.h>

#define FDIM 1024
#define BROWS 16384
#define DELTA_C 0.3f
#define LAMB_C 0.0005f

typedef __bf16 bf8v __attribute__((ext_vector_type(8)));
typedef float f4v __attribute__((ext_vector_type(4)));
typedef int i8v __attribute__((ext_vector_type(8)));
typedef unsigned short u16;
typedef u16 u16x8 __attribute__((ext_vector_type(8)));

// ws layout (bytes):
//   0    : f32 wsf[16] (0=hinge);  64: colsum[1024];  4160: pabs[128];  4672: psq[128]
//   8192 : f32 rowacc[16384] (64KB)
//   131072        : wb8   fp8 [32 kg][1024 n][32B] = 1MB ; wb8[(kg*1024+n)*32+e] = fp8(w[kg*32+e][n])
//   131072+1MB    : sktb8 fp8 [32 kg][16384 m][32B] = 16MB; sktb8[(kg*16384+m)*32+e] = fp8(skt[m][kg*32+e])
#define WS_PABS_OFF 4160
#define WS_PSQ_OFF 4672
#define WS_ROWACC_OFF 8192
#define WS_WB8_OFF 131072
#define WS_SKTB8_OFF (131072 + (1u << 20))
#define WS_NEED ((size_t)WS_SKTB8_OFF + ((size_t)1 << 24))

// single 32KB staging buffer + 512B colsum
#define SMEM_MAIN (32768 + 512)

__device__ __forceinline__ u16 f2bf(float f) {
  unsigned u = __builtin_bit_cast(unsigned, f);
  u += 0x7fffu + ((u >> 16) & 1u);
  return (u16)(u >> 16);
}

__device__ __forceinline__ void gload_lds16(const void* g, void* l) {
  __builtin_amdgcn_global_load_lds(
      (const __attribute__((address_space(1))) unsigned int*)g,
      (__attribute__((address_space(3))) unsigned int*)l, 16, 0, 0);
}

// ---- merged prep: blocks [0,128) = W stats + fp8 wb8; [128,128+2048) = fp8 sktb8 ----
template <bool FULL>
__global__ __launch_bounds__(256) void prep_all(const float* __restrict__ w,
                                                const float* __restrict__ skt,
                                                float* __restrict__ colsum,
                                                float* __restrict__ pabs,
                                                float* __restrict__ psq,
                                                char* __restrict__ wb8,
                                                char* __restrict__ sktb8) {
  __shared__ float red[8];
  const int t = threadIdx.x;
  const int bid = blockIdx.x;

  if (bid < 128) {
    const int b = bid;
    const int k0 = b * 8;
    const int col = t * 4;
    float wv[8][4];

    float cs0 = 0.f, cs1 = 0.f, cs2 = 0.f, cs3 = 0.f;
    float aacc = 0.f, sacc = 0.f;
#pragma unroll
    for (int i = 0; i < 8; ++i) {
      const int gk = k0 + i;
      const float4 v = *(const float4*)(w + (size_t)gk * FDIM + col);
      wv[i][0] = v.x; wv[i][1] = v.y; wv[i][2] = v.z; wv[i][3] = v.w;
      cs0 += v.x; cs1 += v.y; cs2 += v.z; cs3 += v.w;
      const float d0 = v.x - (gk == col + 0 ? 1.f : 0.f);
      const float d1 = v.y - (gk == col + 1 ? 1.f : 0.f);
      const float d2 = v.z - (gk == col + 2 ? 1.f : 0.f);
      const float d3 = v.w - (gk == col + 3 ? 1.f : 0.f);
      aacc += fabsf(d0) + fabsf(d1) + fabsf(d2) + fabsf(d3);
      sacc += d0 * d0 + d1 * d1 + d2 * d2 + d3 * d3;
    }
    atomicAdd(&colsum[col + 0], cs0);
    atomicAdd(&colsum[col + 1], cs1);
    atomicAdd(&colsum[col + 2], cs2);
    atomicAdd(&colsum[col + 3], cs3);
#pragma unroll
    for (int off = 1; off < 64; off <<= 1) {
      aacc += __shfl_xor(aacc, off);
      sacc += __shfl_xor(sacc, off);
    }
    const int wv_ = t >> 6;
    if ((t & 63) == 0) { red[wv_] = aacc; red[4 + wv_] = sacc; }
    __syncthreads();
    if (t == 0) pabs[b] = red[0] + red[1] + red[2] + red[3];
    if (t == 1) psq[b] = red[4] + red[5] + red[6] + red[7];
    if constexpr (FULL) {
      // wb8[(kg*1024+n)*32 + (b&3)*8 + i] = fp8(w[b*8+i][n]),  kg = b>>2
#pragma unroll
      for (int j = 0; j < 4; ++j) {
        int lo = __builtin_amdgcn_cvt_pk_fp8_f32(wv[0][j], wv[1][j], 0, false);
        lo = __builtin_amdgcn_cvt_pk_fp8_f32(wv[2][j], wv[3][j], lo, true);
        int hi = __builtin_amdgcn_cvt_pk_fp8_f32(wv[4][j], wv[5][j], 0, false);
        hi = __builtin_amdgcn_cvt_pk_fp8_f32(wv[6][j], wv[7][j], hi, true);
        int2 pk; pk.x = lo; pk.y = hi;
        *(int2*)(wb8 + ((size_t)(b >> 2) * 1024 + col + j) * 32 + (b & 3) * 8) = pk;
      }
    }
  } else if constexpr (FULL) {
    // A path: block handles 64 m x 128 k; thread (m = t&63, kg = t>>6) converts 32 k
    const int ab = bid - 128;
    const int mb = ab >> 3, kb = ab & 7;
    const int m0 = mb * 64, k0 = kb * 128, kg0 = kb * 4;
    const int m = t & 63, kg = t >> 6;
    const float* sp = skt + (size_t)(m0 + m) * FDIM + k0 + kg * 32;
    int wds[8];
#pragma unroll
    for (int q = 0; q < 4; ++q) {
      const float4 a = *(const float4*)(sp + q * 8);
      const float4 b = *(const float4*)(sp + q * 8 + 4);
      int w0 = __builtin_amdgcn_cvt_pk_fp8_f32(a.x, a.y, 0, false);
      w0 = __builtin_amdgcn_cvt_pk_fp8_f32(a.z, a.w, w0, true);
      int w1 = __builtin_amdgcn_cvt_pk_fp8_f32(b.x, b.y, 0, false);
      w1 = __builtin_amdgcn_cvt_pk_fp8_f32(b.z, b.w, w1, true);
      wds[2 * q] = w0; wds[2 * q + 1] = w1;
    }
    char* dst = sktb8 + ((size_t)(kg0 + kg) * BROWS + m0 + m) * 32;
    int4 lo; lo.x = wds[0]; lo.y = wds[1]; lo.z = wds[2]; lo.w = wds[3];
    int4 hi; hi.x = wds[4]; hi.y = wds[5]; hi.z = wds[6]; hi.w = wds[7];
    *(int4*)dst = lo;
    *(int4*)(dst + 16) = hi;
  }
}

// ---- main: T = skt @ w via MX-fp8 K=128 MFMA (unit scales). BM=BN=128, BK=128,
// 8 k-steps, single 32KB buffer, launch_bounds(256,2) (no allocator squeeze).
// Epilogue: per-wave-private scratch, NO barriers -> compiler pipelines the
// 4 chunks' global loads (the only change vs r19).
__global__ __launch_bounds__(256, 2) void hofel_main_fp8(
    const float* __restrict__ imgp, const float* __restrict__ imgn,
    const char* __restrict__ wb8, const char* __restrict__ sktb8,
    const float* __restrict__ colsum, float* __restrict__ rowacc) {
  extern __shared__ char smem[];
  float* lds_cs = (float*)(smem + 32768);

  const int t = threadIdx.x;
  const int lane = t & 63;
  const int wid = t >> 6;  // 0..3
  const int l15 = lane & 15;
  const int l4 = lane >> 4;

  // XCD swizzle: 1024 blocks; XCD x gets mt in [x*16, x*16+16) (2MB sktb8 slice = L2)
  const int swz = (blockIdx.x & 7) * 128 + (blockIdx.x >> 3);
  const int mt = swz >> 3, ntw = swz & 7;
  const int m0 = mt * 128, n0 = ntw * 128;

  const int wm = (wid >> 1) * 64, wn = (wid & 1) * 64;

  f4v acc[4][4];
#pragma unroll
  for (int mi = 0; mi < 4; ++mi)
#pragma unroll
    for (int ni = 0; ni < 4; ++ni) {
      f4v z = {0.f, 0.f, 0.f, 0.f};
      acc[mi][ni] = z;
    }

  auto stage = [&](int kt) {
#pragma unroll
    for (int r = 0; r < 8; ++r) {
      const int o = r * 4096 + wid * 1024;  // wave-uniform LDS byte offset
      const int ol = o + lane * 16;
      const char* src;
      if (ol < 16384) {  // A: [kg][ch][m][16B]
        const int kg = ol >> 12, ch = (ol >> 11) & 1, m = (ol >> 4) & 127;
        src = sktb8 + ((size_t)(kt * 4 + kg) * BROWS + m0 + m) * 32 + ch * 16;
      } else {           // B: [kg][ch][n][16B]
        const int o2 = ol - 16384;
        const int kg = o2 >> 12, ch = (o2 >> 11) & 1, n = (o2 >> 4) & 127;
        src = wb8 + ((size_t)(kt * 4 + kg) * FDIM + n0 + n) * 32 + ch * 16;
      }
      gload_lds16(src, smem + o);
    }
  };

  // prologue: stage tile 0; colsum -> LDS tail (disjoint from staging region)
  stage(0);
  if (t < 128) lds_cs[t] = colsum[n0 + t];
  __syncthreads();  // drains vmcnt/lgkm -> tile 0 + colsum ready

  for (int kt = 0; kt < 8; ++kt) {
    const char* bA = smem;
    const char* bB = smem + 16384;
    // bF[4] resident (32 VGPRs); aF streamed one at a time (8 VGPRs)
    i8v bF[4];
#pragma unroll
    for (int ni = 0; ni < 4; ++ni) {
      const int row = wn + ni * 16 + l15;
      const int4 lo = *(const int4*)(bB + l4 * 4096 + row * 16);
      const int4 hi = *(const int4*)(bB + l4 * 4096 + 2048 + row * 16);
      i8v v = {lo.x, lo.y, lo.z, lo.w, hi.x, hi.y, hi.z, hi.w};
      bF[ni] = v;
    }
#pragma unroll
    for (int mi = 0; mi < 4; ++mi) {
      const int row = wm + mi * 16 + l15;
      const int4 lo = *(const int4*)(bA + l4 * 4096 + row * 16);
      const int4 hi = *(const int4*)(bA + l4 * 4096 + 2048 + row * 16);
      i8v aF = {lo.x, lo.y, lo.z, lo.w, hi.x, hi.y, hi.z, hi.w};
#pragma unroll
      for (int ni = 0; ni < 4; ++ni)
        acc[mi][ni] = __builtin_amdgcn_mfma_scale_f32_16x16x128_f8f6f4(
            aF, bF[ni], acc[mi][ni], 0, 0, 0, 0x7F7F7F7F, 0, 0x7F7F7F7F);
    }

    if (kt < 7) {
      __syncthreads();  // all waves done reading (frags consumed)
      stage(kt + 1);
      __syncthreads();  // staged data visible (drain)
    }
  }

  __syncthreads();  // staging region free for epilogue scratch

  // ---- vectorized epilogue, per-wave-private scratch, barrier-free ----
  // Each wave owns eT slice [wid*4352, wid*4352+4352); chunks reuse it with
  // within-wave lgkm ordering only -> compiler can hoist chunk mi+1's global
  // loads above chunk mi's FMA chain (4-deep latency pipelining).
  {
    float(*eT)[68] = (float(*)[68])(smem + wid * 4352);  // per-wave 16x68 f32
    const int r = l15, qb = l4;
#pragma unroll
    for (int mi = 0; mi < 4; ++mi) {
#pragma unroll
      for (int ni = 0; ni < 4; ++ni)
#pragma unroll
        for (int rr = 0; rr < 4; ++rr)
          eT[l4 * 4 + rr][ni * 16 + l15] = acc[mi][ni][rr];
      const int rowg = m0 + wm + mi * 16 + r;
      const float* pr = imgp + (size_t)rowg * FDIM + n0 + wn;
      const float* nr = imgn + (size_t)rowg * FDIM + n0 + wn;
      float part = 0.f;
#pragma unroll
      for (int i = 0; i < 4; ++i) {
        const int q = qb + 4 * i;
        const f4v T = *(const f4v*)&eT[r][q * 4];
        const float4 p = *(const float4*)(pr + q * 4);
        const float4 n = *(const float4*)(nr + q * 4);
        const f4v cs = *(const f4v*)&lds_cs[wn + q * 4];
        part += (p.x - n.x) * (-2.f * T[0] + (p.x + n.x) * cs[0]);
        part += (p.y - n.y) * (-2.f * T[1] + (p.y + n.y) * cs[1]);
        part += (p.z - n.z) * (-2.f * T[2] + (p.z + n.z) * cs[2]);
        part += (p.w - n.w) * (-2.f * T[3] + (p.w + n.w) * cs[3]);
      }
      part += __shfl_xor(part, 16);
      part += __shfl_xor(part, 32);
      if (lane < 16) atomicAdd(rowacc + rowg, part);
    }
  }
}

// ---- fallback (no workspace): bf16 in-kernel convert, correctness-only ----
__global__ __launch_bounds__(512, 4) void hofel_fb(
    const float* __restrict__ skt, const float* __restrict__ imgp,
    const float* __restrict__ imgn, const float* __restrict__ w,
    const float* __restrict__ colsum, float* __restrict__ rowacc) {
  __shared__ u16 ldsT[12288];
  __shared__ float lds_cs[128];
  const int t = threadIdx.x, lane = t & 63, wid = t >> 6;
  const int l15 = lane & 15, l4 = lane >> 4;
  const int swz = (blockIdx.x & 7) * 64 + (blockIdx.x >> 3);
  const int mt = swz >> 3, nt = swz & 7;
  const int m0 = mt * 256, n0 = nt * 128;
  const int wm = (wid >> 1) * 64, wn = (wid & 1) * 64;

  if (t < 128) lds_cs[t] = colsum[n0 + t];
  f4v acc[4][4];
#pragma unroll
  for (int mi = 0; mi < 4; ++mi)
#pragma unroll
    for (int ni = 0; ni < 4; ++ni) {
      f4v z = {0.f, 0.f, 0.f, 0.f};
      acc[mi][ni] = z;
    }

  for (int kt = 0; kt < 32; ++kt) {
    __syncthreads();
    {  // B: ldsB[s][kc][e] = w[kt*32+s*8+e][n0+kc]  (strided, correct)
      const int kc = t >> 2, s = t & 3;
      u16x8 pk;
#pragma unroll
      for (int e = 0; e < 8; ++e)
        pk[e] = f2bf(w[(size_t)(kt * 32 + s * 8 + e) * FDIM + n0 + kc]);
      *(u16x8*)((char*)ldsT + 16384 + (s * 128 + kc) * 16) = pk;
    }
    {  // A from f32 skt
      const int m = t >> 1, h = t & 1;
      const float* ap = skt + (size_t)(m0 + m) * FDIM + kt * 32 + h * 16;
#pragma unroll
      for (int q = 0; q < 2; ++q) {
        const float4 v0 = *(const float4*)(ap + q * 8);
        const float4 v1 = *(const float4*)(ap + q * 8 + 4);
        u16x8 pk;
        pk[0] = f2bf(v0.x); pk[1] = f2bf(v0.y); pk[2] = f2bf(v0.z); pk[3] = f2bf(v0.w);
        pk[4] = f2bf(v1.x); pk[5] = f2bf(v1.y); pk[6] = f2bf(v1.z); pk[7] = f2bf(v1.w);
        *(u16x8*)((char*)ldsT + (h * 2 + q) * 4096 + m * 16) = pk;
      }
    }
    __syncthreads();
    bf8v aF[4], bF[4];
#pragma unroll
    for (int mi = 0; mi < 4; ++mi)
      aF[mi] = *(const bf8v*)((char*)ldsT + l4 * 4096 + (wm + mi * 16 + l15) * 16);
#pragma unroll
    for (int ni = 0; ni < 4; ++ni)
      bF[ni] = *(const bf8v*)((char*)ldsT + 16384 + l4 * 2048 + (wn + ni * 16 + l15) * 16);
#pragma unroll
    for (int mi = 0; mi < 4; ++mi)
#pragma unroll
      for (int ni = 0; ni < 4; ++ni)
        acc[mi][ni] = __builtin_amdgcn_mfma_f32_16x16x32_bf16(aF[mi], bF[ni], acc[mi][ni], 0, 0, 0);
  }
  __syncthreads();
  {
    float(*eT)[68] = (float(*)[68])((char*)ldsT + wid * 4352);
    const int r = l15, qb = l4;
#pragma unroll
    for (int mi = 0; mi < 4; ++mi) {
#pragma unroll
      for (int ni = 0; ni < 4; ++ni)
#pragma unroll
        for (int rr = 0; rr < 4; ++rr)
          eT[l4 * 4 + rr][ni * 16 + l15] = acc[mi][ni][rr];
      const int rowg = m0 + wm + mi * 16 + r;
      const float* pr = imgp + (size_t)rowg * FDIM + n0 + wn;
      const float* nr = imgn + (size_t)rowg * FDIM + n0 + wn;
      float part = 0.f;
#pragma unroll
      for (int i = 0; i < 4; ++i) {
        const int q = qb + 4 * i;
        const f4v T = *(const f4v*)&eT[r][q * 4];
        const float4 p = *(const float4*)(pr + q * 4);
        const float4 n = *(const float4*)(nr + q * 4);
        const f4v cs = *(const f4v*)&lds_cs[wn + q * 4];
        part += (p.x - n.x) * (-2.f * T[0] + (p.x + n.x) * cs[0]);
        part += (p.y - n.y) * (-2.f * T[1] + (p.y + n.y) * cs[1]);
        part += (p.z - n.z) * (-2.f * T[2] + (p.z + n.z) * cs[2]);
        part += (p.w - n.w) * (-2.f * T[3] + (p.w + n.w) * cs[3]);
      }
      part += __shfl_xor(part, 16);
      part += __shfl_xor(part, 32);
      if (lane < 16) atomicAdd(rowacc + rowg, part);
      __syncthreads();
    }
  }
}

__global__ __launch_bounds__(1024) void hinge_reduce(const float* __restrict__ rowacc,
                                                     float* __restrict__ wsf) {
  __shared__ float part[16];
  const int t = threadIdx.x;
  const int id = blockIdx.x * 1024 + t;
  float v = fmaxf(DELTA_C + rowacc[id], 0.f);
#pragma unroll
  for (int off = 1; off < 64; off <<= 1) v += __shfl_xor(v, off);
  if ((t & 63) == 0) part[t >> 6] = v;
  __syncthreads();
  if (t < 16) {
    float x = part[t];
#pragma unroll
    for (int off = 1; off < 16; off <<= 1) x += __shfl_xor(x, off);
    if (t == 0) atomicAdd(&wsf[0], x);
  }
}

__global__ __launch_bounds__(128) void finalize_k(const float* __restrict__ wsf,
                                                  const float* __restrict__ pabs,
                                                  const float* __restrict__ psq,
                                                  float* __restrict__ out) {
  __shared__ float ra[2], rs[2];
  const int t = threadIdx.x;
  float a = pabs[t], s = psq[t];
#pragma unroll
  for (int off = 1; off < 64; off <<= 1) {
    a += __shfl_xor(a, off);
    s += __shfl_xor(s, off);
  }
  if ((t & 63) == 0) { ra[t >> 6] = a; rs[t >> 6] = s; }
  __syncthreads();
  if (t == 0)
    out[0] = wsf[0] * (1.f / (float)BROWS) +
             LAMB_C * ((ra[0] + ra[1]) + sqrtf(rs[0] + rs[1]));
}

extern "C" void kernel_launch(void* const* d_in, const int* in_sizes, int n_in,
                              void* d_out, int out_size, void* d_ws, size_t ws_size,
                              hipStream_t stream) {
  const float* skt  = (const float*)d_in[0];
  const float* imgp = (const float*)d_in[1];
  const float* imgn = (const float*)d_in[2];
  const float* w    = (const float*)d_in[3];

  float* wsf = (float*)d_ws;
  float* colsum = wsf + 16;
  float* pabs = (float*)((char*)d_ws + WS_PABS_OFF);
  float* psq = (float*)((char*)d_ws + WS_PSQ_OFF);
  float* rowacc = (float*)((char*)d_ws + WS_ROWACC_OFF);
  char* wb8 = (char*)d_ws + WS_WB8_OFF;
  char* sktb8 = (char*)d_ws + WS_SKTB8_OFF;
  float* out = (float*)d_out;

  // zero wsf + colsum + pabs/psq + rowacc every call (harness doesn't re-poison)
  hipMemsetAsync(d_ws, 0, WS_ROWACC_OFF + BROWS * sizeof(float), stream);

  if (ws_size >= WS_NEED) {
    prep_all<true><<<128 + 2048, 256, 0, stream>>>(w, skt, colsum, pabs, psq, wb8, sktb8);
    (void)hipFuncSetAttribute(reinterpret_cast<const void*>(hofel_main_fp8),
                              hipFuncAttributeMaxDynamicSharedMemorySize, SMEM_MAIN);
    hofel_main_fp8<<<1024, 256, SMEM_MAIN, stream>>>(imgp, imgn, wb8, sktb8, colsum, rowacc);
  } else {
    prep_all<false><<<128, 256, 0, stream>>>(w, skt, colsum, pabs, psq, wb8, sktb8);
    hofel_fb<<<512, 512, 0, stream>>>(skt, imgp, imgn, w, colsum, rowacc);
  }

  hinge_reduce<<<16, 1024, 0, stream>>>(rowacc, wsf);
  finalize_k<<<1, 128, 0, stream>>>(wsf, pabs, psq, out);
}